// Round 1
// baseline (631.758 us; speedup 1.0000x reference)
//
#include <hip/hip_runtime.h>
#include <math.h>

// Problem constants
#define TT 16384   // B*N tokens
#define HH 1024    // hidden
#define DD 2048    // expert inner dim
#define EE 8       // experts
#define MAXT 96    // >= EE + TT/256 (256-row tiles)

typedef float f32x4 __attribute__((ext_vector_type(4)));
typedef __bf16 bf16x8 __attribute__((ext_vector_type(8)));

__device__ __forceinline__ unsigned short f2bf(float f) {
  union { float f; unsigned u; } v; v.f = f;
  unsigned r = v.u + 0x7FFFu + ((v.u >> 16) & 1u);  // RNE
  return (unsigned short)(r >> 16);
}

// async global->LDS 16B per lane; LDS dest = wave-uniform base + lane*16
__device__ __forceinline__ void gl2lds16(const unsigned short* g, unsigned short* l) {
  __builtin_amdgcn_global_load_lds(
      (const __attribute__((address_space(1))) void*)g,
      (__attribute__((address_space(3))) void*)l, 16, 0, 0);
}

// ---------------- init: zero accumulators ----------------
__global__ void k_init(int* counts, float* probs_sum, float* ent_sum) {
  int t = threadIdx.x;
  if (t < EE) { counts[t] = 0; probs_sum[t] = 0.f; }
  if (t == 0) *ent_sum = 0.f;
}

// ---------------- transpose+convert weights: [E][R][C] fp32 -> [E][C][R] bf16 ----------------
__global__ __launch_bounds__(256) void k_transpose(const float* __restrict__ src,
                                                   unsigned short* __restrict__ dst,
                                                   int R, int C) {
  __shared__ float tile[32][33];
  int tilesC = C / 32, tilesR = R / 32;
  int bid = blockIdx.x;
  int e = bid / (tilesR * tilesC);
  int rem = bid % (tilesR * tilesC);
  int tr = rem / tilesC, tc = rem % tilesC;
  const float* s = src + (size_t)e * R * C;
  unsigned short* d = dst + (size_t)e * R * C;
  int tx = threadIdx.x & 31, ty = threadIdx.x >> 5;
#pragma unroll
  for (int i = 0; i < 4; ++i)
    tile[ty + i * 8][tx] = s[(size_t)(tr * 32 + ty + i * 8) * C + tc * 32 + tx];
  __syncthreads();
#pragma unroll
  for (int i = 0; i < 4; ++i) {
    int rr = ty + i * 8;
    d[(size_t)(tc * 32 + rr) * R + tr * 32 + tx] = f2bf(tile[tx][rr]);
  }
}

// ---------------- router: fp64 logits, softmax, argmax, loss partials, x->bf16 fused ----------------
__global__ __launch_bounds__(256) void k_router(const float* __restrict__ x,
                                                const float* __restrict__ Wr,
                                                const float* __restrict__ br,
                                                int* __restrict__ eidx,
                                                float* __restrict__ probs_sum,
                                                float* __restrict__ ent_sum,
                                                int* __restrict__ counts,
                                                unsigned short* __restrict__ xb) {
  __shared__ float s_p[EE];
  __shared__ int   s_c[EE];
  __shared__ float s_e;
  int tid = threadIdx.x;
  if (tid < EE) { s_p[tid] = 0.f; s_c[tid] = 0; }
  if (tid == 0) s_e = 0.f;
  __syncthreads();
  int lane = tid & 63, w = tid >> 6;
  for (int tt = 0; tt < 4; ++tt) {
    int token = blockIdx.x * 16 + w * 4 + tt;
    double acc[EE];
#pragma unroll
    for (int e = 0; e < EE; ++e) acc[e] = 0.0;
    const float* xr = x + (size_t)token * HH;
    unsigned short* xo = xb + (size_t)token * HH;
    for (int i = 0; i < 16; ++i) {
      int hh = i * 64 + lane;
      float xf = xr[hh];
      xo[hh] = f2bf(xf);               // fused fp32->bf16 conversion
      double xv = (double)xf;
      const float* wr = Wr + (size_t)hh * EE;
#pragma unroll
      for (int e = 0; e < EE; ++e) acc[e] += xv * (double)wr[e];
    }
#pragma unroll
    for (int off = 32; off > 0; off >>= 1) {
#pragma unroll
      for (int e = 0; e < EE; ++e) acc[e] += __shfl_down(acc[e], off);
    }
    if (lane == 0) {
      double l[EE];
#pragma unroll
      for (int e = 0; e < EE; ++e) l[e] = acc[e] + (double)br[e];
      double m = l[0]; int am = 0;
#pragma unroll
      for (int e = 1; e < EE; ++e) { if (l[e] > m) { m = l[e]; am = e; } }  // first-max semantics
      double p[EE]; double s = 0.0;
#pragma unroll
      for (int e = 0; e < EE; ++e) { p[e] = exp(l[e] - m); s += p[e]; }
      double inv = 1.0 / s; double ent = 0.0;
#pragma unroll
      for (int e = 0; e < EE; ++e) { p[e] *= inv; ent -= p[e] * log(p[e] + 1e-8); }
      eidx[token] = am;
#pragma unroll
      for (int e = 0; e < EE; ++e) atomicAdd(&s_p[e], (float)p[e]);
      atomicAdd(&s_e, (float)ent);
      atomicAdd(&s_c[am], 1);
    }
  }
  __syncthreads();
  if (tid < EE) { atomicAdd(&probs_sum[tid], s_p[tid]); atomicAdd(&counts[tid], s_c[tid]); }
  if (tid == 0) atomicAdd(ent_sum, s_e);
}

// ---------------- scan: offsets, cursors, 256-row tile descriptors, loss outputs ----------------
__global__ void k_scan(const int* counts, const float* probs_sum, const float* ent_sum,
                       int* offsets, int* cursor,
                       int* tileE, int* tileR0, int* tileEnd, int* nTiles,
                       float* out_scalars) {
  if (threadIdx.x != 0) return;
  int off = 0, nt = 0;
  for (int e = 0; e < EE; ++e) {
    offsets[e] = off; cursor[e] = off;
    int c = counts[e];
    for (int r = 0; r < c; r += 256) {
      tileE[nt] = e; tileR0[nt] = off + r; tileEnd[nt] = off + c; ++nt;
    }
    off += c;
  }
  offsets[EE] = off;
  *nTiles = nt;
  float bal = 0.f;
  for (int e = 0; e < EE; ++e) { float pi = probs_sum[e] / (float)TT; bal += pi * pi; }
  out_scalars[0] = (float)EE * bal;      // balance_loss
  out_scalars[1] = *ent_sum / (float)TT; // entropy_loss
  for (int e = 0; e < EE; ++e) out_scalars[2 + e] = (float)counts[e];  // tokens_per_expert
}

// ---------------- build permutation (expert-grouped token order) ----------------
__global__ __launch_bounds__(256) void k_perm(const int* __restrict__ eidx,
                                              int* cursor, int* __restrict__ perm) {
  int t = blockIdx.x * 256 + threadIdx.x;
  int lane = threadIdx.x & 63;
  int mye = eidx[t];
  int pos = 0;
#pragma unroll
  for (int e = 0; e < EE; ++e) {
    unsigned long long mask = __ballot(mye == e);
    if (mask == 0ull) continue;
    int leader = __ffsll(mask) - 1;
    int base = 0;
    if (lane == leader) base = atomicAdd(&cursor[e], __popcll(mask));
    base = __shfl(base, leader);
    if (mye == e) pos = base + (int)__popcll(mask & ((1ull << lane) - 1ull));
  }
  perm[pos] = t;
}

// ================= 256x256-tile deep-pipelined MFMA GEMMs =================
// 8 waves (2Mx4N), per-wave 128x64 output, BK=32, 4-deep LDS ring (128 KiB).
// Per K-tile: 2 phases x {stage-issue, 4-8 ds_read_b128, s_barrier, lgkmcnt(0),
// setprio(1), 16 MFMA, setprio(0)}; boundary s_waitcnt vmcnt(8) (counted, never 0
// in steady state -> tiles kt+2,kt+3 stay in flight across the raw barrier).
// LDS swizzle: 16B-slot ^= (row>>1)&3 (conflict-free for both frag reads and the
// linear global_load_lds writes, which use the inverse-swizzled global source).

// GEMM1: h = gelu(gather_perm(xb) @ Wt1[e] + b1[e]) -> bf16 hbuf (permuted rows)
__global__ __launch_bounds__(512, 2) void k_gemm1(const unsigned short* __restrict__ xb,
                                                  const unsigned short* __restrict__ Wt1,
                                                  const float* __restrict__ b1,
                                                  const int* __restrict__ perm,
                                                  const int* __restrict__ tileE,
                                                  const int* __restrict__ tileR0,
                                                  const int* __restrict__ tileEnd,
                                                  const int* __restrict__ nTiles,
                                                  unsigned short* __restrict__ hbuf) {
  const int gx = DD / 256;                 // 8
  const int nwg = gx * MAXT;               // 768 (multiple of 8)
  int wg = blockIdx.y * gx + blockIdx.x;
  int wgs = (wg & 7) * (nwg >> 3) + (wg >> 3);   // XCD-chunked, bijective
  int tile = wgs / gx, cblk = wgs % gx;
  if (tile >= *nTiles) return;
  int e = tileE[tile], r0 = tileR0[tile], rend = tileEnd[tile];
  int c0 = cblk * 256;

  __shared__ __align__(16) unsigned short sAB[4][2][8192];  // [ring][A/B][256*32]

  int tid = threadIdx.x, lane = tid & 63, wid = tid >> 6;
  int wr = wid >> 2, wc = wid & 3;
  int l16 = lane & 15, quad = lane >> 4;
  const int fsw  = (quad ^ ((l16 >> 1) & 3)) << 3;           // frag-read slot swizzle (ushorts)
  const int aoff = (wr * 128 + l16) * 32 + fsw;
  const int boff = (wc * 64 + l16) * 32 + fsw;

  // staging: lane covers (row = base + lane>>2, slot = lane&3); global source slot inverse-swizzled
  int srow = lane >> 2;
  const int ssw = (((lane & 3) ^ ((lane >> 3) & 3)) << 3);
  int ra0 = r0 + wid * 16 + srow;        if (ra0 > rend - 1) ra0 = rend - 1;
  int ra1 = r0 + wid * 16 + 128 + srow;  if (ra1 > rend - 1) ra1 = rend - 1;
  const unsigned short* aS0 = xb + (size_t)perm[ra0] * HH + ssw;
  const unsigned short* aS1 = xb + (size_t)perm[ra1] * HH + ssw;
  const unsigned short* bB  = Wt1 + (size_t)e * DD * HH;
  const unsigned short* bS0 = bB + (size_t)(c0 + wid * 16 + srow) * HH + ssw;
  const unsigned short* bS1 = bB + (size_t)(c0 + wid * 16 + 128 + srow) * HH + ssw;
  const int dA0 = wid * 512, dA1 = wid * 512 + 4096;

  f32x4 acc[8][4] = {};
  const int NT = HH / 32;   // 32

  // prologue: stage tiles 0..2 (12 loads/wave), wait oldest 4 (tile 0)
#pragma unroll
  for (int t = 0; t < 3; ++t) {
    gl2lds16(aS0 + t * 32, &sAB[t][0][dA0]);
    gl2lds16(aS1 + t * 32, &sAB[t][0][dA1]);
    gl2lds16(bS0 + t * 32, &sAB[t][1][dA0]);
    gl2lds16(bS1 + t * 32, &sAB[t][1][dA1]);
  }
  asm volatile("s_waitcnt vmcnt(8)" ::: "memory");
  __builtin_amdgcn_s_barrier();

#pragma unroll 4
  for (int kt = 0; kt < NT; ++kt) {
    const unsigned short* A = &sAB[kt & 3][0][0];
    const unsigned short* B = &sAB[kt & 3][1][0];
    int ts = kt + 3;
    bf16x8 av[4], bv[4];
    // ---- phase 1: issue A-stage of tile kt+3, compute i=0..3 ----
    if (ts < NT) {
      gl2lds16(aS0 + ts * 32, &sAB[ts & 3][0][dA0]);
      gl2lds16(aS1 + ts * 32, &sAB[ts & 3][0][dA1]);
    }
#pragma unroll
    for (int i = 0; i < 4; ++i) av[i] = *(const bf16x8*)(A + aoff + i * 512);
#pragma unroll
    for (int j = 0; j < 4; ++j) bv[j] = *(const bf16x8*)(B + boff + j * 512);
    __builtin_amdgcn_s_barrier();
    asm volatile("s_waitcnt lgkmcnt(0)");
    __builtin_amdgcn_sched_barrier(0);
    __builtin_amdgcn_s_setprio(1);
#pragma unroll
    for (int i = 0; i < 4; ++i)
#pragma unroll
      for (int j = 0; j < 4; ++j)
        acc[i][j] = __builtin_amdgcn_mfma_f32_16x16x32_bf16(av[i], bv[j], acc[i][j], 0, 0, 0);
    __builtin_amdgcn_s_setprio(0);
    __builtin_amdgcn_s_barrier();
    // ---- phase 2: issue B-stage of tile kt+3, compute i=4..7 (bv reused) ----
    if (ts < NT) {
      gl2lds16(bS0 + ts * 32, &sAB[ts & 3][1][dA0]);
      gl2lds16(bS1 + ts * 32, &sAB[ts & 3][1][dA1]);
    }
#pragma unroll
    for (int i = 0; i < 4; ++i) av[i] = *(const bf16x8*)(A + aoff + (i + 4) * 512);
    __builtin_amdgcn_s_barrier();
    asm volatile("s_waitcnt lgkmcnt(0)");
    __builtin_amdgcn_sched_barrier(0);
    __builtin_amdgcn_s_setprio(1);
#pragma unroll
    for (int i = 0; i < 4; ++i)
#pragma unroll
      for (int j = 0; j < 4; ++j)
        acc[i + 4][j] = __builtin_amdgcn_mfma_f32_16x16x32_bf16(av[i], bv[j], acc[i + 4][j], 0, 0, 0);
    __builtin_amdgcn_s_setprio(0);
    // ---- boundary: counted vmcnt (tiles kt+2,kt+3 stay in flight), raw barrier ----
    if (kt < NT - 3)       asm volatile("s_waitcnt vmcnt(8)" ::: "memory");
    else if (kt == NT - 3) asm volatile("s_waitcnt vmcnt(4)" ::: "memory");
    else if (kt == NT - 2) asm volatile("s_waitcnt vmcnt(0)" ::: "memory");
    __builtin_amdgcn_s_barrier();
  }

  float bias[4];
#pragma unroll
  for (int j = 0; j < 4; ++j) bias[j] = b1[e * DD + c0 + wc * 64 + j * 16 + l16];
#pragma unroll
  for (int i = 0; i < 8; ++i) {
#pragma unroll
    for (int r = 0; r < 4; ++r) {
      int gr = r0 + wr * 128 + i * 16 + quad * 4 + r;
      if (gr < rend) {
#pragma unroll
        for (int j = 0; j < 4; ++j) {
          int col = c0 + wc * 64 + j * 16 + l16;
          float v = acc[i][j][r] + bias[j];
          v = 0.5f * v * (1.0f + erff(v * 0.70710678118654752f));  // exact erf GELU
          hbuf[(size_t)gr * DD + col] = f2bf(v);
        }
      }
    }
  }
}

// GEMM2: out[perm[row]] = x + h @ Wt2[e] + b2[e]  (A rows contiguous in hbuf)
__global__ __launch_bounds__(512, 2) void k_gemm2(const unsigned short* __restrict__ hbuf,
                                                  const unsigned short* __restrict__ Wt2,
                                                  const float* __restrict__ b2,
                                                  const float* __restrict__ x,
                                                  const int* __restrict__ perm,
                                                  const int* __restrict__ tileE,
                                                  const int* __restrict__ tileR0,
                                                  const int* __restrict__ tileEnd,
                                                  const int* __restrict__ nTiles,
                                                  float* __restrict__ outp) {
  const int gx = HH / 256;                 // 4
  const int nwg = gx * MAXT;               // 384 (multiple of 8)
  int wg = blockIdx.y * gx + blockIdx.x;
  int wgs = (wg & 7) * (nwg >> 3) + (wg >> 3);
  int tile = wgs / gx, cblk = wgs % gx;
  if (tile >= *nTiles) return;
  int e = tileE[tile], r0 = tileR0[tile], rend = tileEnd[tile];
  int c0 = cblk * 256;

  __shared__ __align__(16) unsigned short sAB[4][2][8192];

  int tid = threadIdx.x, lane = tid & 63, wid = tid >> 6;
  int wr = wid >> 2, wc = wid & 3;
  int l16 = lane & 15, quad = lane >> 4;
  const int fsw  = (quad ^ ((l16 >> 1) & 3)) << 3;
  const int aoff = (wr * 128 + l16) * 32 + fsw;
  const int boff = (wc * 64 + l16) * 32 + fsw;

  int srow = lane >> 2;
  const int ssw = (((lane & 3) ^ ((lane >> 3) & 3)) << 3);
  int ra0 = r0 + wid * 16 + srow;        if (ra0 > rend - 1) ra0 = rend - 1;
  int ra1 = r0 + wid * 16 + 128 + srow;  if (ra1 > rend - 1) ra1 = rend - 1;
  const unsigned short* aS0 = hbuf + (size_t)ra0 * DD + ssw;
  const unsigned short* aS1 = hbuf + (size_t)ra1 * DD + ssw;
  const unsigned short* bB  = Wt2 + (size_t)e * HH * DD;
  const unsigned short* bS0 = bB + (size_t)(c0 + wid * 16 + srow) * DD + ssw;
  const unsigned short* bS1 = bB + (size_t)(c0 + wid * 16 + 128 + srow) * DD + ssw;
  const int dA0 = wid * 512, dA1 = wid * 512 + 4096;

  f32x4 acc[8][4] = {};
  const int NT = DD / 32;   // 64

#pragma unroll
  for (int t = 0; t < 3; ++t) {
    gl2lds16(aS0 + t * 32, &sAB[t][0][dA0]);
    gl2lds16(aS1 + t * 32, &sAB[t][0][dA1]);
    gl2lds16(bS0 + t * 32, &sAB[t][1][dA0]);
    gl2lds16(bS1 + t * 32, &sAB[t][1][dA1]);
  }
  asm volatile("s_waitcnt vmcnt(8)" ::: "memory");
  __builtin_amdgcn_s_barrier();

#pragma unroll 4
  for (int kt = 0; kt < NT; ++kt) {
    const unsigned short* A = &sAB[kt & 3][0][0];
    const unsigned short* B = &sAB[kt & 3][1][0];
    int ts = kt + 3;
    bf16x8 av[4], bv[4];
    if (ts < NT) {
      gl2lds16(aS0 + ts * 32, &sAB[ts & 3][0][dA0]);
      gl2lds16(aS1 + ts * 32, &sAB[ts & 3][0][dA1]);
    }
#pragma unroll
    for (int i = 0; i < 4; ++i) av[i] = *(const bf16x8*)(A + aoff + i * 512);
#pragma unroll
    for (int j = 0; j < 4; ++j) bv[j] = *(const bf16x8*)(B + boff + j * 512);
    __builtin_amdgcn_s_barrier();
    asm volatile("s_waitcnt lgkmcnt(0)");
    __builtin_amdgcn_sched_barrier(0);
    __builtin_amdgcn_s_setprio(1);
#pragma unroll
    for (int i = 0; i < 4; ++i)
#pragma unroll
      for (int j = 0; j < 4; ++j)
        acc[i][j] = __builtin_amdgcn_mfma_f32_16x16x32_bf16(av[i], bv[j], acc[i][j], 0, 0, 0);
    __builtin_amdgcn_s_setprio(0);
    __builtin_amdgcn_s_barrier();
    if (ts < NT) {
      gl2lds16(bS0 + ts * 32, &sAB[ts & 3][1][dA0]);
      gl2lds16(bS1 + ts * 32, &sAB[ts & 3][1][dA1]);
    }
#pragma unroll
    for (int i = 0; i < 4; ++i) av[i] = *(const bf16x8*)(A + aoff + (i + 4) * 512);
    __builtin_amdgcn_s_barrier();
    asm volatile("s_waitcnt lgkmcnt(0)");
    __builtin_amdgcn_sched_barrier(0);
    __builtin_amdgcn_s_setprio(1);
#pragma unroll
    for (int i = 0; i < 4; ++i)
#pragma unroll
      for (int j = 0; j < 4; ++j)
        acc[i + 4][j] = __builtin_amdgcn_mfma_f32_16x16x32_bf16(av[i], bv[j], acc[i + 4][j], 0, 0, 0);
    __builtin_amdgcn_s_setprio(0);
    if (kt < NT - 3)       asm volatile("s_waitcnt vmcnt(8)" ::: "memory");
    else if (kt == NT - 3) asm volatile("s_waitcnt vmcnt(4)" ::: "memory");
    else if (kt == NT - 2) asm volatile("s_waitcnt vmcnt(0)" ::: "memory");
    __builtin_amdgcn_s_barrier();
  }

  float bias[4];
#pragma unroll
  for (int j = 0; j < 4; ++j) bias[j] = b2[e * HH + c0 + wc * 64 + j * 16 + l16];
#pragma unroll
  for (int i = 0; i < 8; ++i) {
#pragma unroll
    for (int r = 0; r < 4; ++r) {
      int gr = r0 + wr * 128 + i * 16 + quad * 4 + r;
      if (gr < rend) {
        int tok = perm[gr];
#pragma unroll
        for (int j = 0; j < 4; ++j) {
          int col = c0 + wc * 64 + j * 16 + l16;
          size_t oi = (size_t)tok * HH + col;
          outp[oi] = x[oi] + bias[j] + acc[i][j][r];
        }
      }
    }
  }
}

extern "C" void kernel_launch(void* const* d_in, const int* in_sizes, int n_in,
                              void* d_out, int out_size, void* d_ws, size_t ws_size,
                              hipStream_t stream) {
  const float* x  = (const float*)d_in[0];
  const float* Wr = (const float*)d_in[1];
  const float* br = (const float*)d_in[2];
  const float* W1 = (const float*)d_in[3];
  const float* b1 = (const float*)d_in[4];
  const float* W2 = (const float*)d_in[5];
  const float* b2 = (const float*)d_in[6];
  float* outp = (float*)d_out;

  char* ws = (char*)d_ws;
  int*   counts    = (int*)(ws + 0);
  int*   cursor    = (int*)(ws + 64);
  int*   nTiles    = (int*)(ws + 128);
  float* probs_sum = (float*)(ws + 192);
  float* ent_sum   = (float*)(ws + 256);
  int*   offsets   = (int*)(ws + 320);
  int*   tileE     = (int*)(ws + 512);
  int*   tileR0    = (int*)(ws + 2048);
  int*   tileEnd   = (int*)(ws + 3584);
  int*   eidx      = (int*)(ws + 8192);
  int*   perm      = (int*)(ws + 8192 + 4 * (size_t)TT);
  size_t off = 8192 + 8 * (size_t)TT;
  unsigned short* xb   = (unsigned short*)(ws + off); off += (size_t)TT * HH * 2;        // 32 MB
  unsigned short* Wt1  = (unsigned short*)(ws + off); off += (size_t)EE * DD * HH * 2;   // 32 MB
  unsigned short* Wt2  = (unsigned short*)(ws + off); off += (size_t)EE * HH * DD * 2;   // 32 MB
  unsigned short* hbuf = (unsigned short*)(ws + off); off += (size_t)TT * DD * 2;        // 64 MB

  k_init<<<1, 64, 0, stream>>>(counts, probs_sum, ent_sum);
  k_transpose<<<EE * (HH / 32) * (DD / 32), 256, 0, stream>>>(W1, Wt1, HH, DD);
  k_transpose<<<EE * (DD / 32) * (HH / 32), 256, 0, stream>>>(W2, Wt2, DD, HH);
  k_router<<<TT / 16, 256, 0, stream>>>(x, Wr, br, eidx, probs_sum, ent_sum, counts, xb);
  k_scan<<<1, 64, 0, stream>>>(counts, probs_sum, ent_sum, offsets, cursor,
                               tileE, tileR0, tileEnd, nTiles, outp + (size_t)TT * HH);
  k_perm<<<TT / 256, 256, 0, stream>>>(eidx, cursor, perm);
  dim3 g1(DD / 256, MAXT);
  k_gemm1<<<g1, 512, 0, stream>>>(xb, Wt1, b1, perm, tileE, tileR0, tileEnd, nTiles, hbuf);
  dim3 g2(HH / 256, MAXT);
  k_gemm2<<<g2, 512, 0, stream>>>(hbuf, Wt2, b2, x, perm, tileE, tileR0, tileEnd, nTiles, outp);
}

// Round 2
// 629.020 us; speedup vs baseline: 1.0044x; 1.0044x over previous
//
#include <hip/hip_runtime.h>
#include <math.h>

// Problem constants
#define TT 16384   // B*N tokens
#define HH 1024    // hidden
#define DD 2048    // expert inner dim
#define EE 8       // experts
#define MAXT 96    // >= EE + TT/256 (256-row tiles)

typedef float f32x4 __attribute__((ext_vector_type(4)));
typedef __bf16 bf16x8 __attribute__((ext_vector_type(8)));

__device__ __forceinline__ unsigned short f2bf(float f) {
  union { float f; unsigned u; } v; v.f = f;
  unsigned r = v.u + 0x7FFFu + ((v.u >> 16) & 1u);  // RNE
  return (unsigned short)(r >> 16);
}

// async global->LDS 16B per lane; LDS dest = wave-uniform base + lane*16
__device__ __forceinline__ void gl2lds16(const unsigned short* g, unsigned short* l) {
  __builtin_amdgcn_global_load_lds(
      (const __attribute__((address_space(1))) void*)g,
      (__attribute__((address_space(3))) void*)l, 16, 0, 0);
}

// ---------------- init: zero accumulators ----------------
__global__ void k_init(int* counts, float* probs_sum, float* ent_sum) {
  int t = threadIdx.x;
  if (t < EE) { counts[t] = 0; probs_sum[t] = 0.f; }
  if (t == 0) *ent_sum = 0.f;
}

// ---------------- transpose+convert weights: [E][R][C] fp32 -> [E][C][R] bf16 ----------------
__global__ __launch_bounds__(256) void k_transpose(const float* __restrict__ src,
                                                   unsigned short* __restrict__ dst,
                                                   int R, int C) {
  __shared__ float tile[32][33];
  int tilesC = C / 32, tilesR = R / 32;
  int bid = blockIdx.x;
  int e = bid / (tilesR * tilesC);
  int rem = bid % (tilesR * tilesC);
  int tr = rem / tilesC, tc = rem % tilesC;
  const float* s = src + (size_t)e * R * C;
  unsigned short* d = dst + (size_t)e * R * C;
  int tx = threadIdx.x & 31, ty = threadIdx.x >> 5;
#pragma unroll
  for (int i = 0; i < 4; ++i)
    tile[ty + i * 8][tx] = s[(size_t)(tr * 32 + ty + i * 8) * C + tc * 32 + tx];
  __syncthreads();
#pragma unroll
  for (int i = 0; i < 4; ++i) {
    int rr = ty + i * 8;
    d[(size_t)(tc * 32 + rr) * R + tr * 32 + tx] = f2bf(tile[tx][rr]);
  }
}

// ---------------- router: fp64 logits, softmax, argmax, loss partials, x->bf16 fused ----------------
__global__ __launch_bounds__(256) void k_router(const float* __restrict__ x,
                                                const float* __restrict__ Wr,
                                                const float* __restrict__ br,
                                                int* __restrict__ eidx,
                                                float* __restrict__ probs_sum,
                                                float* __restrict__ ent_sum,
                                                int* __restrict__ counts,
                                                unsigned short* __restrict__ xb) {
  __shared__ float s_p[EE];
  __shared__ int   s_c[EE];
  __shared__ float s_e;
  int tid = threadIdx.x;
  if (tid < EE) { s_p[tid] = 0.f; s_c[tid] = 0; }
  if (tid == 0) s_e = 0.f;
  __syncthreads();
  int lane = tid & 63, w = tid >> 6;
  for (int tt = 0; tt < 4; ++tt) {
    int token = blockIdx.x * 16 + w * 4 + tt;
    double acc[EE];
#pragma unroll
    for (int e = 0; e < EE; ++e) acc[e] = 0.0;
    const float* xr = x + (size_t)token * HH;
    unsigned short* xo = xb + (size_t)token * HH;
    for (int i = 0; i < 16; ++i) {
      int hh = i * 64 + lane;
      float xf = xr[hh];
      xo[hh] = f2bf(xf);               // fused fp32->bf16 conversion
      double xv = (double)xf;
      const float* wr = Wr + (size_t)hh * EE;
#pragma unroll
      for (int e = 0; e < EE; ++e) acc[e] += xv * (double)wr[e];
    }
#pragma unroll
    for (int off = 32; off > 0; off >>= 1) {
#pragma unroll
      for (int e = 0; e < EE; ++e) acc[e] += __shfl_down(acc[e], off);
    }
    if (lane == 0) {
      double l[EE];
#pragma unroll
      for (int e = 0; e < EE; ++e) l[e] = acc[e] + (double)br[e];
      double m = l[0]; int am = 0;
#pragma unroll
      for (int e = 1; e < EE; ++e) { if (l[e] > m) { m = l[e]; am = e; } }  // first-max semantics
      double p[EE]; double s = 0.0;
#pragma unroll
      for (int e = 0; e < EE; ++e) { p[e] = exp(l[e] - m); s += p[e]; }
      double inv = 1.0 / s; double ent = 0.0;
#pragma unroll
      for (int e = 0; e < EE; ++e) { p[e] *= inv; ent -= p[e] * log(p[e] + 1e-8); }
      eidx[token] = am;
#pragma unroll
      for (int e = 0; e < EE; ++e) atomicAdd(&s_p[e], (float)p[e]);
      atomicAdd(&s_e, (float)ent);
      atomicAdd(&s_c[am], 1);
    }
  }
  __syncthreads();
  if (tid < EE) { atomicAdd(&probs_sum[tid], s_p[tid]); atomicAdd(&counts[tid], s_c[tid]); }
  if (tid == 0) atomicAdd(ent_sum, s_e);
}

// ---------------- scan: offsets, cursors, 256-row tile descriptors, loss outputs ----------------
__global__ void k_scan(const int* counts, const float* probs_sum, const float* ent_sum,
                       int* offsets, int* cursor,
                       int* tileE, int* tileR0, int* tileEnd, int* nTiles,
                       float* out_scalars) {
  if (threadIdx.x != 0) return;
  int off = 0, nt = 0;
  for (int e = 0; e < EE; ++e) {
    offsets[e] = off; cursor[e] = off;
    int c = counts[e];
    for (int r = 0; r < c; r += 256) {
      tileE[nt] = e; tileR0[nt] = off + r; tileEnd[nt] = off + c; ++nt;
    }
    off += c;
  }
  offsets[EE] = off;
  *nTiles = nt;
  float bal = 0.f;
  for (int e = 0; e < EE; ++e) { float pi = probs_sum[e] / (float)TT; bal += pi * pi; }
  out_scalars[0] = (float)EE * bal;      // balance_loss
  out_scalars[1] = *ent_sum / (float)TT; // entropy_loss
  for (int e = 0; e < EE; ++e) out_scalars[2 + e] = (float)counts[e];  // tokens_per_expert
}

// ---------------- build permutation (expert-grouped token order) ----------------
__global__ __launch_bounds__(256) void k_perm(const int* __restrict__ eidx,
                                              int* cursor, int* __restrict__ perm) {
  int t = blockIdx.x * 256 + threadIdx.x;
  int lane = threadIdx.x & 63;
  int mye = eidx[t];
  int pos = 0;
#pragma unroll
  for (int e = 0; e < EE; ++e) {
    unsigned long long mask = __ballot(mye == e);
    if (mask == 0ull) continue;
    int leader = __ffsll(mask) - 1;
    int base = 0;
    if (lane == leader) base = atomicAdd(&cursor[e], __popcll(mask));
    base = __shfl(base, leader);
    if (mye == e) pos = base + (int)__popcll(mask & ((1ull << lane) - 1ull));
  }
  perm[pos] = t;
}

// ================= 256x256-tile deep-pipelined MFMA GEMMs =================
// 8 waves (2Mx4N), per-wave 128x64 output, BK=32, 4-deep LDS ring (128 KiB).
// Per K-tile: 2 phases x {stage-issue, 4-8 ds_read_b128, s_barrier, lgkmcnt(0),
// setprio(1), 16 MFMA, setprio(0)}; boundary s_waitcnt vmcnt(8) (counted, never 0
// in steady state -> tiles kt+2,kt+3 stay in flight across the raw barrier).
// LDS swizzle: 16B-slot ^= (row>>1)&3 (conflict-free for both frag reads and the
// linear global_load_lds writes, which use the inverse-swizzled global source).
// Block mapping: tile = blockIdx.y, cblk = blockIdx.x -> working blocks are the
// contiguous linear-id prefix [0, nTiles*gx), round-robined evenly over all 8
// XCDs by HW dispatch. (Round-1's padded-grid XCD swizzle starved XCDs 6-7 and
// serialized 2-3 blocks/CU on the rest: dur 179us, Occupancy 10%.)

// GEMM1: h = gelu(gather_perm(xb) @ Wt1[e] + b1[e]) -> bf16 hbuf (permuted rows)
__global__ __launch_bounds__(512, 2) void k_gemm1(const unsigned short* __restrict__ xb,
                                                  const unsigned short* __restrict__ Wt1,
                                                  const float* __restrict__ b1,
                                                  const int* __restrict__ perm,
                                                  const int* __restrict__ tileE,
                                                  const int* __restrict__ tileR0,
                                                  const int* __restrict__ tileEnd,
                                                  const int* __restrict__ nTiles,
                                                  unsigned short* __restrict__ hbuf) {
  int tile = blockIdx.y, cblk = blockIdx.x;
  if (tile >= *nTiles) return;
  int e = tileE[tile], r0 = tileR0[tile], rend = tileEnd[tile];
  int c0 = cblk * 256;

  __shared__ __align__(16) unsigned short sAB[4][2][8192];  // [ring][A/B][256*32]

  int tid = threadIdx.x, lane = tid & 63, wid = tid >> 6;
  int wr = wid >> 2, wc = wid & 3;
  int l16 = lane & 15, quad = lane >> 4;
  const int fsw  = (quad ^ ((l16 >> 1) & 3)) << 3;           // frag-read slot swizzle (ushorts)
  const int aoff = (wr * 128 + l16) * 32 + fsw;
  const int boff = (wc * 64 + l16) * 32 + fsw;

  // staging: lane covers (row = base + lane>>2, slot = lane&3); global source slot inverse-swizzled
  int srow = lane >> 2;
  const int ssw = (((lane & 3) ^ ((lane >> 3) & 3)) << 3);
  int ra0 = r0 + wid * 16 + srow;        if (ra0 > rend - 1) ra0 = rend - 1;
  int ra1 = r0 + wid * 16 + 128 + srow;  if (ra1 > rend - 1) ra1 = rend - 1;
  const unsigned short* aS0 = xb + (size_t)perm[ra0] * HH + ssw;
  const unsigned short* aS1 = xb + (size_t)perm[ra1] * HH + ssw;
  const unsigned short* bB  = Wt1 + (size_t)e * DD * HH;
  const unsigned short* bS0 = bB + (size_t)(c0 + wid * 16 + srow) * HH + ssw;
  const unsigned short* bS1 = bB + (size_t)(c0 + wid * 16 + 128 + srow) * HH + ssw;
  const int dA0 = wid * 512, dA1 = wid * 512 + 4096;

  f32x4 acc[8][4] = {};
  const int NT = HH / 32;   // 32

  // prologue: stage tiles 0..2 (12 loads/wave), wait oldest 4 (tile 0)
#pragma unroll
  for (int t = 0; t < 3; ++t) {
    gl2lds16(aS0 + t * 32, &sAB[t][0][dA0]);
    gl2lds16(aS1 + t * 32, &sAB[t][0][dA1]);
    gl2lds16(bS0 + t * 32, &sAB[t][1][dA0]);
    gl2lds16(bS1 + t * 32, &sAB[t][1][dA1]);
  }
  asm volatile("s_waitcnt vmcnt(8)" ::: "memory");
  __builtin_amdgcn_s_barrier();

#pragma unroll 4
  for (int kt = 0; kt < NT; ++kt) {
    const unsigned short* A = &sAB[kt & 3][0][0];
    const unsigned short* B = &sAB[kt & 3][1][0];
    int ts = kt + 3;
    bf16x8 av[4], bv[4];
    // ---- phase 1: issue A-stage of tile kt+3, compute i=0..3 ----
    if (ts < NT) {
      gl2lds16(aS0 + ts * 32, &sAB[ts & 3][0][dA0]);
      gl2lds16(aS1 + ts * 32, &sAB[ts & 3][0][dA1]);
    }
#pragma unroll
    for (int i = 0; i < 4; ++i) av[i] = *(const bf16x8*)(A + aoff + i * 512);
#pragma unroll
    for (int j = 0; j < 4; ++j) bv[j] = *(const bf16x8*)(B + boff + j * 512);
    __builtin_amdgcn_s_barrier();
    asm volatile("s_waitcnt lgkmcnt(0)");
    __builtin_amdgcn_sched_barrier(0);
    __builtin_amdgcn_s_setprio(1);
#pragma unroll
    for (int i = 0; i < 4; ++i)
#pragma unroll
      for (int j = 0; j < 4; ++j)
        acc[i][j] = __builtin_amdgcn_mfma_f32_16x16x32_bf16(av[i], bv[j], acc[i][j], 0, 0, 0);
    __builtin_amdgcn_s_setprio(0);
    __builtin_amdgcn_s_barrier();
    // ---- phase 2: issue B-stage of tile kt+3, compute i=4..7 (bv reused) ----
    if (ts < NT) {
      gl2lds16(bS0 + ts * 32, &sAB[ts & 3][1][dA0]);
      gl2lds16(bS1 + ts * 32, &sAB[ts & 3][1][dA1]);
    }
#pragma unroll
    for (int i = 0; i < 4; ++i) av[i] = *(const bf16x8*)(A + aoff + (i + 4) * 512);
    __builtin_amdgcn_s_barrier();
    asm volatile("s_waitcnt lgkmcnt(0)");
    __builtin_amdgcn_sched_barrier(0);
    __builtin_amdgcn_s_setprio(1);
#pragma unroll
    for (int i = 0; i < 4; ++i)
#pragma unroll
      for (int j = 0; j < 4; ++j)
        acc[i + 4][j] = __builtin_amdgcn_mfma_f32_16x16x32_bf16(av[i], bv[j], acc[i + 4][j], 0, 0, 0);
    __builtin_amdgcn_s_setprio(0);
    // ---- boundary: counted vmcnt (tiles kt+2,kt+3 stay in flight), raw barrier ----
    if (kt < NT - 3)       asm volatile("s_waitcnt vmcnt(8)" ::: "memory");
    else if (kt == NT - 3) asm volatile("s_waitcnt vmcnt(4)" ::: "memory");
    else if (kt == NT - 2) asm volatile("s_waitcnt vmcnt(0)" ::: "memory");
    __builtin_amdgcn_s_barrier();
  }

  float bias[4];
#pragma unroll
  for (int j = 0; j < 4; ++j) bias[j] = b1[e * DD + c0 + wc * 64 + j * 16 + l16];
#pragma unroll
  for (int i = 0; i < 8; ++i) {
#pragma unroll
    for (int r = 0; r < 4; ++r) {
      int gr = r0 + wr * 128 + i * 16 + quad * 4 + r;
      if (gr < rend) {
#pragma unroll
        for (int j = 0; j < 4; ++j) {
          int col = c0 + wc * 64 + j * 16 + l16;
          float v = acc[i][j][r] + bias[j];
          v = 0.5f * v * (1.0f + erff(v * 0.70710678118654752f));  // exact erf GELU
          hbuf[(size_t)gr * DD + col] = f2bf(v);
        }
      }
    }
  }
}

// GEMM2: out[perm[row]] = x + h @ Wt2[e] + b2[e]  (A rows contiguous in hbuf)
__global__ __launch_bounds__(512, 2) void k_gemm2(const unsigned short* __restrict__ hbuf,
                                                  const unsigned short* __restrict__ Wt2,
                                                  const float* __restrict__ b2,
                                                  const float* __restrict__ x,
                                                  const int* __restrict__ perm,
                                                  const int* __restrict__ tileE,
                                                  const int* __restrict__ tileR0,
                                                  const int* __restrict__ tileEnd,
                                                  const int* __restrict__ nTiles,
                                                  float* __restrict__ outp) {
  int tile = blockIdx.y, cblk = blockIdx.x;
  if (tile >= *nTiles) return;
  int e = tileE[tile], r0 = tileR0[tile], rend = tileEnd[tile];
  int c0 = cblk * 256;

  __shared__ __align__(16) unsigned short sAB[4][2][8192];

  int tid = threadIdx.x, lane = tid & 63, wid = tid >> 6;
  int wr = wid >> 2, wc = wid & 3;
  int l16 = lane & 15, quad = lane >> 4;
  const int fsw  = (quad ^ ((l16 >> 1) & 3)) << 3;
  const int aoff = (wr * 128 + l16) * 32 + fsw;
  const int boff = (wc * 64 + l16) * 32 + fsw;

  int srow = lane >> 2;
  const int ssw = (((lane & 3) ^ ((lane >> 3) & 3)) << 3);
  int ra0 = r0 + wid * 16 + srow;        if (ra0 > rend - 1) ra0 = rend - 1;
  int ra1 = r0 + wid * 16 + 128 + srow;  if (ra1 > rend - 1) ra1 = rend - 1;
  const unsigned short* aS0 = hbuf + (size_t)ra0 * DD + ssw;
  const unsigned short* aS1 = hbuf + (size_t)ra1 * DD + ssw;
  const unsigned short* bB  = Wt2 + (size_t)e * HH * DD;
  const unsigned short* bS0 = bB + (size_t)(c0 + wid * 16 + srow) * DD + ssw;
  const unsigned short* bS1 = bB + (size_t)(c0 + wid * 16 + 128 + srow) * DD + ssw;
  const int dA0 = wid * 512, dA1 = wid * 512 + 4096;

  f32x4 acc[8][4] = {};
  const int NT = DD / 32;   // 64

#pragma unroll
  for (int t = 0; t < 3; ++t) {
    gl2lds16(aS0 + t * 32, &sAB[t][0][dA0]);
    gl2lds16(aS1 + t * 32, &sAB[t][0][dA1]);
    gl2lds16(bS0 + t * 32, &sAB[t][1][dA0]);
    gl2lds16(bS1 + t * 32, &sAB[t][1][dA1]);
  }
  asm volatile("s_waitcnt vmcnt(8)" ::: "memory");
  __builtin_amdgcn_s_barrier();

#pragma unroll 4
  for (int kt = 0; kt < NT; ++kt) {
    const unsigned short* A = &sAB[kt & 3][0][0];
    const unsigned short* B = &sAB[kt & 3][1][0];
    int ts = kt + 3;
    bf16x8 av[4], bv[4];
    if (ts < NT) {
      gl2lds16(aS0 + ts * 32, &sAB[ts & 3][0][dA0]);
      gl2lds16(aS1 + ts * 32, &sAB[ts & 3][0][dA1]);
    }
#pragma unroll
    for (int i = 0; i < 4; ++i) av[i] = *(const bf16x8*)(A + aoff + i * 512);
#pragma unroll
    for (int j = 0; j < 4; ++j) bv[j] = *(const bf16x8*)(B + boff + j * 512);
    __builtin_amdgcn_s_barrier();
    asm volatile("s_waitcnt lgkmcnt(0)");
    __builtin_amdgcn_sched_barrier(0);
    __builtin_amdgcn_s_setprio(1);
#pragma unroll
    for (int i = 0; i < 4; ++i)
#pragma unroll
      for (int j = 0; j < 4; ++j)
        acc[i][j] = __builtin_amdgcn_mfma_f32_16x16x32_bf16(av[i], bv[j], acc[i][j], 0, 0, 0);
    __builtin_amdgcn_s_setprio(0);
    __builtin_amdgcn_s_barrier();
    if (ts < NT) {
      gl2lds16(bS0 + ts * 32, &sAB[ts & 3][1][dA0]);
      gl2lds16(bS1 + ts * 32, &sAB[ts & 3][1][dA1]);
    }
#pragma unroll
    for (int i = 0; i < 4; ++i) av[i] = *(const bf16x8*)(A + aoff + (i + 4) * 512);
    __builtin_amdgcn_s_barrier();
    asm volatile("s_waitcnt lgkmcnt(0)");
    __builtin_amdgcn_sched_barrier(0);
    __builtin_amdgcn_s_setprio(1);
#pragma unroll
    for (int i = 0; i < 4; ++i)
#pragma unroll
      for (int j = 0; j < 4; ++j)
        acc[i + 4][j] = __builtin_amdgcn_mfma_f32_16x16x32_bf16(av[i], bv[j], acc[i + 4][j], 0, 0, 0);
    __builtin_amdgcn_s_setprio(0);
    if (kt < NT - 3)       asm volatile("s_waitcnt vmcnt(8)" ::: "memory");
    else if (kt == NT - 3) asm volatile("s_waitcnt vmcnt(4)" ::: "memory");
    else if (kt == NT - 2) asm volatile("s_waitcnt vmcnt(0)" ::: "memory");
    __builtin_amdgcn_s_barrier();
  }

  float bias[4];
#pragma unroll
  for (int j = 0; j < 4; ++j) bias[j] = b2[e * HH + c0 + wc * 64 + j * 16 + l16];
#pragma unroll
  for (int i = 0; i < 8; ++i) {
#pragma unroll
    for (int r = 0; r < 4; ++r) {
      int gr = r0 + wr * 128 + i * 16 + quad * 4 + r;
      if (gr < rend) {
        int tok = perm[gr];
#pragma unroll
        for (int j = 0; j < 4; ++j) {
          int col = c0 + wc * 64 + j * 16 + l16;
          size_t oi = (size_t)tok * HH + col;
          outp[oi] = x[oi] + bias[j] + acc[i][j][r];
        }
      }
    }
  }
}

extern "C" void kernel_launch(void* const* d_in, const int* in_sizes, int n_in,
                              void* d_out, int out_size, void* d_ws, size_t ws_size,
                              hipStream_t stream) {
  const float* x  = (const float*)d_in[0];
  const float* Wr = (const float*)d_in[1];
  const float* br = (const float*)d_in[2];
  const float* W1 = (const float*)d_in[3];
  const float* b1 = (const float*)d_in[4];
  const float* W2 = (const float*)d_in[5];
  const float* b2 = (const float*)d_in[6];
  float* outp = (float*)d_out;

  char* ws = (char*)d_ws;
  int*   counts    = (int*)(ws + 0);
  int*   cursor    = (int*)(ws + 64);
  int*   nTiles    = (int*)(ws + 128);
  float* probs_sum = (float*)(ws + 192);
  float* ent_sum   = (float*)(ws + 256);
  int*   offsets   = (int*)(ws + 320);
  int*   tileE     = (int*)(ws + 512);
  int*   tileR0    = (int*)(ws + 2048);
  int*   tileEnd   = (int*)(ws + 3584);
  int*   eidx      = (int*)(ws + 8192);
  int*   perm      = (int*)(ws + 8192 + 4 * (size_t)TT);
  size_t off = 8192 + 8 * (size_t)TT;
  unsigned short* xb   = (unsigned short*)(ws + off); off += (size_t)TT * HH * 2;        // 32 MB
  unsigned short* Wt1  = (unsigned short*)(ws + off); off += (size_t)EE * DD * HH * 2;   // 32 MB
  unsigned short* Wt2  = (unsigned short*)(ws + off); off += (size_t)EE * HH * DD * 2;   // 32 MB
  unsigned short* hbuf = (unsigned short*)(ws + off); off += (size_t)TT * DD * 2;        // 64 MB

  k_init<<<1, 64, 0, stream>>>(counts, probs_sum, ent_sum);
  k_transpose<<<EE * (HH / 32) * (DD / 32), 256, 0, stream>>>(W1, Wt1, HH, DD);
  k_transpose<<<EE * (DD / 32) * (HH / 32), 256, 0, stream>>>(W2, Wt2, DD, HH);
  k_router<<<TT / 16, 256, 0, stream>>>(x, Wr, br, eidx, probs_sum, ent_sum, counts, xb);
  k_scan<<<1, 64, 0, stream>>>(counts, probs_sum, ent_sum, offsets, cursor,
                               tileE, tileR0, tileEnd, nTiles, outp + (size_t)TT * HH);
  k_perm<<<TT / 256, 256, 0, stream>>>(eidx, cursor, perm);
  dim3 g1(DD / 256, MAXT);
  k_gemm1<<<g1, 512, 0, stream>>>(xb, Wt1, b1, perm, tileE, tileR0, tileEnd, nTiles, hbuf);
  dim3 g2(HH / 256, MAXT);
  k_gemm2<<<g2, 512, 0, stream>>>(hbuf, Wt2, b2, x, perm, tileE, tileR0, tileEnd, nTiles, outp);
}

// Round 3
// 599.221 us; speedup vs baseline: 1.0543x; 1.0497x over previous
//
#include <hip/hip_runtime.h>
#include <math.h>

// Problem constants
#define TT 16384   // B*N tokens
#define HH 1024    // hidden
#define DD 2048    // expert inner dim
#define EE 8       // experts
#define MAXT 96    // >= EE + TT/256 (256-row tiles)

typedef float f32x4 __attribute__((ext_vector_type(4)));
typedef __bf16 bf16x8 __attribute__((ext_vector_type(8)));

__device__ __forceinline__ unsigned short f2bf(float f) {
  union { float f; unsigned u; } v; v.f = f;
  unsigned r = v.u + 0x7FFFu + ((v.u >> 16) & 1u);  // RNE
  return (unsigned short)(r >> 16);
}

// async global->LDS 16B per lane; LDS dest = wave-uniform base, HW adds lane*16
__device__ __forceinline__ void gl2lds16(const unsigned short* g, unsigned short* l) {
  __builtin_amdgcn_global_load_lds(
      (const __attribute__((address_space(1))) void*)g,
      (__attribute__((address_space(3))) void*)l, 16, 0, 0);
}

// ---------------- init: zero accumulators ----------------
__global__ void k_init(int* counts, float* probs_sum, float* ent_sum) {
  int t = threadIdx.x;
  if (t < EE) { counts[t] = 0; probs_sum[t] = 0.f; }
  if (t == 0) *ent_sum = 0.f;
}

// ---------------- transpose+convert weights: [E][R][C] fp32 -> [E][C][R] bf16 ----------------
__global__ __launch_bounds__(256) void k_transpose(const float* __restrict__ src,
                                                   unsigned short* __restrict__ dst,
                                                   int R, int C) {
  __shared__ float tile[32][33];
  int tilesC = C / 32, tilesR = R / 32;
  int bid = blockIdx.x;
  int e = bid / (tilesR * tilesC);
  int rem = bid % (tilesR * tilesC);
  int tr = rem / tilesC, tc = rem % tilesC;
  const float* s = src + (size_t)e * R * C;
  unsigned short* d = dst + (size_t)e * R * C;
  int tx = threadIdx.x & 31, ty = threadIdx.x >> 5;
#pragma unroll
  for (int i = 0; i < 4; ++i)
    tile[ty + i * 8][tx] = s[(size_t)(tr * 32 + ty + i * 8) * C + tc * 32 + tx];
  __syncthreads();
#pragma unroll
  for (int i = 0; i < 4; ++i) {
    int rr = ty + i * 8;
    d[(size_t)(tc * 32 + rr) * R + tr * 32 + tx] = f2bf(tile[tx][rr]);
  }
}

// ---------------- router: fp64 logits, softmax, argmax, loss partials, x->bf16 fused ----------------
__global__ __launch_bounds__(256) void k_router(const float* __restrict__ x,
                                                const float* __restrict__ Wr,
                                                const float* __restrict__ br,
                                                int* __restrict__ eidx,
                                                float* __restrict__ probs_sum,
                                                float* __restrict__ ent_sum,
                                                int* __restrict__ counts,
                                                unsigned short* __restrict__ xb) {
  __shared__ float s_p[EE];
  __shared__ int   s_c[EE];
  __shared__ float s_e;
  int tid = threadIdx.x;
  if (tid < EE) { s_p[tid] = 0.f; s_c[tid] = 0; }
  if (tid == 0) s_e = 0.f;
  __syncthreads();
  int lane = tid & 63, w = tid >> 6;
  for (int tt = 0; tt < 4; ++tt) {
    int token = blockIdx.x * 16 + w * 4 + tt;
    double acc[EE];
#pragma unroll
    for (int e = 0; e < EE; ++e) acc[e] = 0.0;
    const float* xr = x + (size_t)token * HH;
    unsigned short* xo = xb + (size_t)token * HH;
    for (int i = 0; i < 16; ++i) {
      int hh = i * 64 + lane;
      float xf = xr[hh];
      xo[hh] = f2bf(xf);               // fused fp32->bf16 conversion
      double xv = (double)xf;
      const float* wr = Wr + (size_t)hh * EE;
#pragma unroll
      for (int e = 0; e < EE; ++e) acc[e] += xv * (double)wr[e];
    }
#pragma unroll
    for (int off = 32; off > 0; off >>= 1) {
#pragma unroll
      for (int e = 0; e < EE; ++e) acc[e] += __shfl_down(acc[e], off);
    }
    if (lane == 0) {
      double l[EE];
#pragma unroll
      for (int e = 0; e < EE; ++e) l[e] = acc[e] + (double)br[e];
      double m = l[0]; int am = 0;
#pragma unroll
      for (int e = 1; e < EE; ++e) { if (l[e] > m) { m = l[e]; am = e; } }  // first-max semantics
      double p[EE]; double s = 0.0;
#pragma unroll
      for (int e = 0; e < EE; ++e) { p[e] = exp(l[e] - m); s += p[e]; }
      double inv = 1.0 / s; double ent = 0.0;
#pragma unroll
      for (int e = 0; e < EE; ++e) { p[e] *= inv; ent -= p[e] * log(p[e] + 1e-8); }
      eidx[token] = am;
#pragma unroll
      for (int e = 0; e < EE; ++e) atomicAdd(&s_p[e], (float)p[e]);
      atomicAdd(&s_e, (float)ent);
      atomicAdd(&s_c[am], 1);
    }
  }
  __syncthreads();
  if (tid < EE) { atomicAdd(&probs_sum[tid], s_p[tid]); atomicAdd(&counts[tid], s_c[tid]); }
  if (tid == 0) atomicAdd(ent_sum, s_e);
}

// ---------------- scan: offsets, cursors, 256-row tile descriptors, loss outputs ----------------
__global__ void k_scan(const int* counts, const float* probs_sum, const float* ent_sum,
                       int* offsets, int* cursor,
                       int* tileE, int* tileR0, int* tileEnd, int* nTiles,
                       float* out_scalars) {
  if (threadIdx.x != 0) return;
  int off = 0, nt = 0;
  for (int e = 0; e < EE; ++e) {
    offsets[e] = off; cursor[e] = off;
    int c = counts[e];
    for (int r = 0; r < c; r += 256) {
      tileE[nt] = e; tileR0[nt] = off + r; tileEnd[nt] = off + c; ++nt;
    }
    off += c;
  }
  offsets[EE] = off;
  *nTiles = nt;
  float bal = 0.f;
  for (int e = 0; e < EE; ++e) { float pi = probs_sum[e] / (float)TT; bal += pi * pi; }
  out_scalars[0] = (float)EE * bal;      // balance_loss
  out_scalars[1] = *ent_sum / (float)TT; // entropy_loss
  for (int e = 0; e < EE; ++e) out_scalars[2 + e] = (float)counts[e];  // tokens_per_expert
}

// ---------------- build permutation (expert-grouped token order) ----------------
__global__ __launch_bounds__(256) void k_perm(const int* __restrict__ eidx,
                                              int* cursor, int* __restrict__ perm) {
  int t = blockIdx.x * 256 + threadIdx.x;
  int lane = threadIdx.x & 63;
  int mye = eidx[t];
  int pos = 0;
#pragma unroll
  for (int e = 0; e < EE; ++e) {
    unsigned long long mask = __ballot(mye == e);
    if (mask == 0ull) continue;
    int leader = __ffsll(mask) - 1;
    int base = 0;
    if (lane == leader) base = atomicAdd(&cursor[e], __popcll(mask));
    base = __shfl(base, leader);
    if (mye == e) pos = base + (int)__popcll(mask & ((1ull << lane) - 1ull));
  }
  perm[pos] = t;
}

// ================= 256x128-tile minimal-2-phase MFMA GEMMs =================
// TLP-first design (rounds 1-2 showed 1-block/CU lockstep loses to co-resident
// blocks): BM=256 x BN=128, BK=32, 512 threads (8 waves, 4Mx2N, 64x64/wave,
// acc[4][4]). LDS = 2 x (A 16K + B 8K) = 48 KiB; __launch_bounds__(512,4)
// caps VGPR at 128 -> 2 blocks/CU co-resident; staging stalls of one block
// overlap MFMA of the other (m114 TLP).
// Per K-tile (T3-min, ONE barrier): ds_read cur frags -> stage kt+1 ->
// lgkmcnt(0) -> setprio(1) 16 MFMA setprio(0) -> vmcnt(0) -> s_barrier.
// Loads for kt+1 issued a full tile before use -> latency covered by cur
// tile's LDS+MFMA even if compiler inserts conservative vmcnt waits.
// LDS swizzle (verified 0 conflicts, rounds 1-2): physical 16B slot p at row r
// holds logical slot p ^ ((r>>1)&3); staged via inverse-swizzled global source
// (gl2lds dest stays linear), read with fsw on the frag address.

// GEMM1: h = gelu(gather_perm(xb) @ Wt1[e] + b1[e]) -> bf16 hbuf (permuted rows)
__global__ __launch_bounds__(512, 4) void k_gemm1(const unsigned short* __restrict__ xb,
                                                  const unsigned short* __restrict__ Wt1,
                                                  const float* __restrict__ b1,
                                                  const int* __restrict__ perm,
                                                  const int* __restrict__ tileE,
                                                  const int* __restrict__ tileR0,
                                                  const int* __restrict__ tileEnd,
                                                  const int* __restrict__ nTiles,
                                                  unsigned short* __restrict__ hbuf) {
  int tile = blockIdx.y, cblk = blockIdx.x;
  if (tile >= *nTiles) return;
  int e = tileE[tile], r0 = tileR0[tile], rend = tileEnd[tile];
  int c0 = cblk * 128;

  __shared__ __align__(16) unsigned short sA[2][256 * 32];
  __shared__ __align__(16) unsigned short sB[2][128 * 32];

  int tid = threadIdx.x, lane = tid & 63, wid = tid >> 6;
  int wr = wid >> 1, wc = wid & 1;
  int l16 = lane & 15, quad = lane >> 4;
  const int fsw  = (quad ^ ((l16 >> 1) & 3)) << 3;   // frag-read slot swizzle (ushorts)
  const int aoff = (wr * 64 + l16) * 32 + fsw;
  const int boff = (wc * 64 + l16) * 32 + fsw;

  // staging: thread covers (row = tid>>2, 16B slot = tid&3); source slot inverse-swizzled
  const int ssw = (((tid & 3) ^ ((tid >> 3) & 3)) << 3);
  int row0 = r0 + (tid >> 2);        if (row0 > rend - 1) row0 = rend - 1;
  int row1 = r0 + 128 + (tid >> 2);  if (row1 > rend - 1) row1 = rend - 1;
  const unsigned short* aG0 = xb + (size_t)perm[row0] * HH + ssw;
  const unsigned short* aG1 = xb + (size_t)perm[row1] * HH + ssw;
  const unsigned short* bG  = Wt1 + (size_t)e * DD * HH + (size_t)(c0 + (tid >> 2)) * HH + ssw;
  const int dstA0 = wid * 512, dstA1 = 4096 + wid * 512, dstB = wid * 512;  // wave-uniform

  f32x4 acc[4][4] = {};
  const int NT = HH / 32;   // 32

  gl2lds16(aG0, &sA[0][dstA0]);
  gl2lds16(aG1, &sA[0][dstA1]);
  gl2lds16(bG,  &sB[0][dstB]);
  asm volatile("s_waitcnt vmcnt(0)" ::: "memory");
  __builtin_amdgcn_s_barrier();

#pragma unroll 2
  for (int kt = 0; kt < NT; ++kt) {
    const unsigned short* A = &sA[kt & 1][0];
    const unsigned short* B = &sB[kt & 1][0];
    bf16x8 av[4], bv[4];
#pragma unroll
    for (int i = 0; i < 4; ++i) av[i] = *(const bf16x8*)(A + aoff + i * 512);
#pragma unroll
    for (int j = 0; j < 4; ++j) bv[j] = *(const bf16x8*)(B + boff + j * 512);
    if (kt + 1 < NT) {
      int nb = (kt + 1) & 1, ko = (kt + 1) * 32;
      gl2lds16(aG0 + ko, &sA[nb][dstA0]);
      gl2lds16(aG1 + ko, &sA[nb][dstA1]);
      gl2lds16(bG  + ko, &sB[nb][dstB]);
    }
    asm volatile("s_waitcnt lgkmcnt(0)");
    __builtin_amdgcn_sched_barrier(0);
    __builtin_amdgcn_s_setprio(1);
#pragma unroll
    for (int i = 0; i < 4; ++i)
#pragma unroll
      for (int j = 0; j < 4; ++j)
        acc[i][j] = __builtin_amdgcn_mfma_f32_16x16x32_bf16(av[i], bv[j], acc[i][j], 0, 0, 0);
    __builtin_amdgcn_s_setprio(0);
    asm volatile("s_waitcnt vmcnt(0)" ::: "memory");
    __builtin_amdgcn_s_barrier();
  }

  float bias[4];
#pragma unroll
  for (int j = 0; j < 4; ++j) bias[j] = b1[e * DD + c0 + wc * 64 + j * 16 + l16];
#pragma unroll
  for (int i = 0; i < 4; ++i) {
#pragma unroll
    for (int r = 0; r < 4; ++r) {
      int gr = r0 + wr * 64 + i * 16 + quad * 4 + r;
      if (gr < rend) {
#pragma unroll
        for (int j = 0; j < 4; ++j) {
          int col = c0 + wc * 64 + j * 16 + l16;
          float v = acc[i][j][r] + bias[j];
          v = 0.5f * v * (1.0f + erff(v * 0.70710678118654752f));  // exact erf GELU
          hbuf[(size_t)gr * DD + col] = f2bf(v);
        }
      }
    }
  }
}

// GEMM2: out[perm[row]] = x + h @ Wt2[e] + b2[e]  (A rows contiguous in hbuf)
__global__ __launch_bounds__(512, 4) void k_gemm2(const unsigned short* __restrict__ hbuf,
                                                  const unsigned short* __restrict__ Wt2,
                                                  const float* __restrict__ b2,
                                                  const float* __restrict__ x,
                                                  const int* __restrict__ perm,
                                                  const int* __restrict__ tileE,
                                                  const int* __restrict__ tileR0,
                                                  const int* __restrict__ tileEnd,
                                                  const int* __restrict__ nTiles,
                                                  float* __restrict__ outp) {
  int tile = blockIdx.y, cblk = blockIdx.x;
  if (tile >= *nTiles) return;
  int e = tileE[tile], r0 = tileR0[tile], rend = tileEnd[tile];
  int c0 = cblk * 128;

  __shared__ __align__(16) unsigned short sA[2][256 * 32];
  __shared__ __align__(16) unsigned short sB[2][128 * 32];

  int tid = threadIdx.x, lane = tid & 63, wid = tid >> 6;
  int wr = wid >> 1, wc = wid & 1;
  int l16 = lane & 15, quad = lane >> 4;
  const int fsw  = (quad ^ ((l16 >> 1) & 3)) << 3;
  const int aoff = (wr * 64 + l16) * 32 + fsw;
  const int boff = (wc * 64 + l16) * 32 + fsw;

  const int ssw = (((tid & 3) ^ ((tid >> 3) & 3)) << 3);
  int row0 = r0 + (tid >> 2);        if (row0 > rend - 1) row0 = rend - 1;
  int row1 = r0 + 128 + (tid >> 2);  if (row1 > rend - 1) row1 = rend - 1;
  const unsigned short* aG0 = hbuf + (size_t)row0 * DD + ssw;
  const unsigned short* aG1 = hbuf + (size_t)row1 * DD + ssw;
  const unsigned short* bG  = Wt2 + (size_t)e * HH * DD + (size_t)(c0 + (tid >> 2)) * DD + ssw;
  const int dstA0 = wid * 512, dstA1 = 4096 + wid * 512, dstB = wid * 512;

  f32x4 acc[4][4] = {};
  const int NT = DD / 32;   // 64

  gl2lds16(aG0, &sA[0][dstA0]);
  gl2lds16(aG1, &sA[0][dstA1]);
  gl2lds16(bG,  &sB[0][dstB]);
  asm volatile("s_waitcnt vmcnt(0)" ::: "memory");
  __builtin_amdgcn_s_barrier();

#pragma unroll 2
  for (int kt = 0; kt < NT; ++kt) {
    const unsigned short* A = &sA[kt & 1][0];
    const unsigned short* B = &sB[kt & 1][0];
    bf16x8 av[4], bv[4];
#pragma unroll
    for (int i = 0; i < 4; ++i) av[i] = *(const bf16x8*)(A + aoff + i * 512);
#pragma unroll
    for (int j = 0; j < 4; ++j) bv[j] = *(const bf16x8*)(B + boff + j * 512);
    if (kt + 1 < NT) {
      int nb = (kt + 1) & 1, ko = (kt + 1) * 32;
      gl2lds16(aG0 + ko, &sA[nb][dstA0]);
      gl2lds16(aG1 + ko, &sA[nb][dstA1]);
      gl2lds16(bG  + ko, &sB[nb][dstB]);
    }
    asm volatile("s_waitcnt lgkmcnt(0)");
    __builtin_amdgcn_sched_barrier(0);
    __builtin_amdgcn_s_setprio(1);
#pragma unroll
    for (int i = 0; i < 4; ++i)
#pragma unroll
      for (int j = 0; j < 4; ++j)
        acc[i][j] = __builtin_amdgcn_mfma_f32_16x16x32_bf16(av[i], bv[j], acc[i][j], 0, 0, 0);
    __builtin_amdgcn_s_setprio(0);
    asm volatile("s_waitcnt vmcnt(0)" ::: "memory");
    __builtin_amdgcn_s_barrier();
  }

  float bias[4];
#pragma unroll
  for (int j = 0; j < 4; ++j) bias[j] = b2[e * HH + c0 + wc * 64 + j * 16 + l16];
#pragma unroll
  for (int i = 0; i < 4; ++i) {
#pragma unroll
    for (int r = 0; r < 4; ++r) {
      int gr = r0 + wr * 64 + i * 16 + quad * 4 + r;
      if (gr < rend) {
        int tok = perm[gr];
#pragma unroll
        for (int j = 0; j < 4; ++j) {
          int col = c0 + wc * 64 + j * 16 + l16;
          size_t oi = (size_t)tok * HH + col;
          outp[oi] = x[oi] + bias[j] + acc[i][j][r];
        }
      }
    }
  }
}

extern "C" void kernel_launch(void* const* d_in, const int* in_sizes, int n_in,
                              void* d_out, int out_size, void* d_ws, size_t ws_size,
                              hipStream_t stream) {
  const float* x  = (const float*)d_in[0];
  const float* Wr = (const float*)d_in[1];
  const float* br = (const float*)d_in[2];
  const float* W1 = (const float*)d_in[3];
  const float* b1 = (const float*)d_in[4];
  const float* W2 = (const float*)d_in[5];
  const float* b2 = (const float*)d_in[6];
  float* outp = (float*)d_out;

  char* ws = (char*)d_ws;
  int*   counts    = (int*)(ws + 0);
  int*   cursor    = (int*)(ws + 64);
  int*   nTiles    = (int*)(ws + 128);
  float* probs_sum = (float*)(ws + 192);
  float* ent_sum   = (float*)(ws + 256);
  int*   offsets   = (int*)(ws + 320);
  int*   tileE     = (int*)(ws + 512);
  int*   tileR0    = (int*)(ws + 2048);
  int*   tileEnd   = (int*)(ws + 3584);
  int*   eidx      = (int*)(ws + 8192);
  int*   perm      = (int*)(ws + 8192 + 4 * (size_t)TT);
  size_t off = 8192 + 8 * (size_t)TT;
  unsigned short* xb   = (unsigned short*)(ws + off); off += (size_t)TT * HH * 2;        // 32 MB
  unsigned short* Wt1  = (unsigned short*)(ws + off); off += (size_t)EE * DD * HH * 2;   // 32 MB
  unsigned short* Wt2  = (unsigned short*)(ws + off); off += (size_t)EE * HH * DD * 2;   // 32 MB
  unsigned short* hbuf = (unsigned short*)(ws + off); off += (size_t)TT * DD * 2;        // 64 MB

  k_init<<<1, 64, 0, stream>>>(counts, probs_sum, ent_sum);
  k_transpose<<<EE * (HH / 32) * (DD / 32), 256, 0, stream>>>(W1, Wt1, HH, DD);
  k_transpose<<<EE * (DD / 32) * (HH / 32), 256, 0, stream>>>(W2, Wt2, DD, HH);
  k_router<<<TT / 16, 256, 0, stream>>>(x, Wr, br, eidx, probs_sum, ent_sum, counts, xb);
  k_scan<<<1, 64, 0, stream>>>(counts, probs_sum, ent_sum, offsets, cursor,
                               tileE, tileR0, tileEnd, nTiles, outp + (size_t)TT * HH);
  k_perm<<<TT / 256, 256, 0, stream>>>(eidx, cursor, perm);
  dim3 g1(DD / 128, MAXT);
  k_gemm1<<<g1, 512, 0, stream>>>(xb, Wt1, b1, perm, tileE, tileR0, tileEnd, nTiles, hbuf);
  dim3 g2(HH / 128, MAXT);
  k_gemm2<<<g2, 512, 0, stream>>>(hbuf, Wt2, b2, x, perm, tileE, tileR0, tileEnd, nTiles, outp);
}